// Round 1
// baseline (268.303 us; speedup 1.0000x reference)
//
#include <hip/hip_runtime.h>

typedef float  f32x4  __attribute__((ext_vector_type(4)));
typedef __bf16 bf16x8 __attribute__((ext_vector_type(8)));
typedef short  s16x8  __attribute__((ext_vector_type(8)));

static __device__ __forceinline__ unsigned short f2bf(float f) {
  unsigned u = __builtin_bit_cast(unsigned, f);
  u += 0x7FFFu + ((u >> 16) & 1u);          // RNE
  return (unsigned short)(u >> 16);
}

static __device__ __forceinline__ f32x4 mfma16(s16x8 a, s16x8 b, f32x4 c) {
  return __builtin_amdgcn_mfma_f32_16x16x32_bf16(
      __builtin_bit_cast(bf16x8, a), __builtin_bit_cast(bf16x8, b), c, 0, 0, 0);
}

static __device__ __forceinline__ void gll16(const void* g, void* lds) {
  __builtin_amdgcn_global_load_lds(
      (const __attribute__((address_space(1))) unsigned int*)g,
      (__attribute__((address_space(3))) unsigned int*)lds, 16, 0, 0);
}

// ---------------------------------------------------------------------------
// K0: x[B,C,H,W] fp32 -> xb[m][c] bf16, m = window-shifted token order.
// m = ((b*16+wy)*16+wx)*64 + iy*8 + ix ; src pixel y=(wy*8+iy+4)&127, x likewise.
__global__ __launch_bounds__(256) void k_conv_x(const float* __restrict__ x,
                                                unsigned short* __restrict__ xb) {
  __shared__ __align__(16) unsigned short tile[64 * 264];  // +8 pad: aligned rows
  int widx = blockIdx.x;
  int b = widx >> 8, wy = (widx >> 4) & 15, wx = widx & 15;
  int t = threadIdx.x;
  int tok = t & 63, cq = t >> 6;            // wave-uniform cq
  int iy = tok >> 3, ix = tok & 7;
  int y  = (wy * 8 + iy + 4) & 127;
  int xx = (wx * 8 + ix + 4) & 127;
  const float* px = x + ((size_t)b << 22) + (y << 7) + xx;
  for (int ci = 0; ci < 64; ++ci) {
    int c = ci * 4 + cq;
    tile[tok * 264 + c] = f2bf(px[(size_t)c << 14]);
  }
  __syncthreads();
  size_t base = (size_t)widx * 64 * 256;
  for (int it = 0; it < 8; ++it) {
    int idx = it * 256 + t;
    int tk = idx >> 5, ch = idx & 31;
    uint4 v = *reinterpret_cast<const uint4*>(&tile[tk * 264 + ch * 8]);
    *reinterpret_cast<uint4*>(&xb[base + (size_t)tk * 256 + ch * 8]) = v;
  }
}

// ---------------------------------------------------------------------------
// K0b: weight transposes -> K-minor bf16. blocks 0..767: wqkvT, 768..1023: woutT
__global__ __launch_bounds__(256) void k_conv_w(const float* __restrict__ wqkv,
                                                const float* __restrict__ wout,
                                                unsigned short* __restrict__ wqkvT,
                                                unsigned short* __restrict__ woutT) {
  int j = blockIdx.x, c = threadIdx.x;
  if (j < 768) wqkvT[j * 256 + c] = f2bf(wqkv[c * 768 + j]);
  else { int jj = j - 768; woutT[jj * 256 + c] = f2bf(wout[c * 256 + jj]); }
}

// ---------------------------------------------------------------------------
// K1: QKV GEMM  out[m][j] = xb[m][:]·W[:,j] + b, M=65536, N=768, K=256.
// 128x128 tile, BK=64, 4 waves (2x2 of 64x64), global_load_lds + XOR swizzle.
// Store: t<2 (Q,K): [win][t][h][seq][cc]; t==2 (V): [win][2][h][cc][seq] (transposed)
__global__ __launch_bounds__(256) void k_qkv(const unsigned short* __restrict__ xb,
                                             const unsigned short* __restrict__ wT,
                                             const float* __restrict__ bqkv,
                                             unsigned short* __restrict__ qkv) {
  __shared__ __align__(16) unsigned short Al[128 * 64];
  __shared__ __align__(16) unsigned short Bl[128 * 64];
  int j0 = blockIdx.x * 128, m0 = blockIdx.y * 128;
  int lane = threadIdx.x & 63, w = threadIdx.x >> 6;
  int wm = w >> 1, wn = w & 1, g = lane >> 4, l15 = lane & 15;

  f32x4 acc[4][4];
#pragma unroll
  for (int i = 0; i < 4; ++i)
#pragma unroll
    for (int j = 0; j < 4; ++j) acc[i][j] = f32x4{0.f, 0.f, 0.f, 0.f};

  for (int kt = 0; kt < 4; ++kt) {
    int k0 = kt * 64;
#pragma unroll
    for (int i = 0; i < 4; ++i) {
      int r0 = (w * 4 + i) * 8;                 // wave-uniform dest rows
      int row = r0 + (lane >> 3);
      int sg = (lane & 7) ^ (row & 7);          // pre-swizzled source chunk
      gll16(xb + (size_t)(m0 + row) * 256 + k0 + sg * 8, &Al[r0 * 64]);
      gll16(wT + (size_t)(j0 + row) * 256 + k0 + sg * 8, &Bl[r0 * 64]);
    }
    __syncthreads();
#pragma unroll
    for (int ks = 0; ks < 2; ++ks) {
      s16x8 af[4], bf[4];
#pragma unroll
      for (int mi = 0; mi < 4; ++mi) {
        int row = wm * 64 + mi * 16 + l15;
        int chunk = (ks * 4 + g) ^ (row & 7);
        af[mi] = *reinterpret_cast<const s16x8*>(&Al[row * 64 + chunk * 8]);
      }
#pragma unroll
      for (int ni = 0; ni < 4; ++ni) {
        int row = wn * 64 + ni * 16 + l15;
        int chunk = (ks * 4 + g) ^ (row & 7);
        bf[ni] = *reinterpret_cast<const s16x8*>(&Bl[row * 64 + chunk * 8]);
      }
#pragma unroll
      for (int mi = 0; mi < 4; ++mi)
#pragma unroll
        for (int ni = 0; ni < 4; ++ni)
          acc[mi][ni] = mfma16(af[mi], bf[ni], acc[mi][ni]);
    }
    __syncthreads();
  }

  int t3 = j0 >> 8;  // which of q/k/v this n-tile belongs to (128 | 256)
#pragma unroll
  for (int ni = 0; ni < 4; ++ni) {
    int j = j0 + wn * 64 + ni * 16 + l15;
    int h = (j >> 5) & 7, cc = j & 31;
    float bj = bqkv[j];
#pragma unroll
    for (int mi = 0; mi < 4; ++mi) {
      int mb = m0 + wm * 64 + mi * 16 + g * 4;
      int win = mb >> 6, seq0 = mb & 63;
      size_t basead = ((size_t)(win * 3 + t3) * 8 + h) * 2048;
      f32x4 v = acc[mi][ni];
      if (t3 < 2) {
#pragma unroll
        for (int r = 0; r < 4; ++r)
          qkv[basead + (size_t)(seq0 + r) * 32 + cc] = f2bf(v[r] + bj);
      } else {
        ushort4 pk;
        pk.x = f2bf(v.x + bj); pk.y = f2bf(v.y + bj);
        pk.z = f2bf(v.z + bj); pk.w = f2bf(v.w + bj);
        *reinterpret_cast<ushort4*>(&qkv[basead + (size_t)cc * 64 + seq0]) = pk;
      }
    }
  }
}

// ---------------------------------------------------------------------------
// K2: windowed attention. 1 block per window, 4 waves x 2 heads each.
// Per wave LDS (12KB): Q[64][32]swz3 | K[64][32]swz3 | Vt[32][64]swz7 ; P[64][64]swz7 overlays Q+K.
__global__ __launch_bounds__(256) void k_attn(const unsigned short* __restrict__ qkv,
                                              const float* __restrict__ btab,
                                              unsigned short* __restrict__ ao) {
  __shared__ __align__(16) unsigned char sm[4 * 12288];
  int win = blockIdx.x;
  int lane = threadIdx.x & 63, w = threadIdx.x >> 6;
  unsigned char* base = sm + w * 12288;
  unsigned short* Qb = (unsigned short*)(base);
  unsigned short* Kb = (unsigned short*)(base + 4096);
  unsigned short* Vb = (unsigned short*)(base + 8192);
  int g = lane >> 4, l15 = lane & 15;
  const float scale = 0.17677669529663687f;  // 1/sqrt(32)

  for (int hi = 0; hi < 2; ++hi) {
    int h = w + hi * 4;
    const unsigned short* Qg = qkv + ((size_t)(win * 3 + 0) * 8 + h) * 2048;
    const unsigned short* Kg = qkv + ((size_t)(win * 3 + 1) * 8 + h) * 2048;
    const unsigned short* Vg = qkv + ((size_t)(win * 3 + 2) * 8 + h) * 2048;
#pragma unroll
    for (int i = 0; i < 4; ++i) {
      int cL = i * 64 + lane;
      { int row = cL >> 2, ch = (cL & 3) ^ (row & 3);
        gll16(Qg + row * 32 + ch * 8, Qb + i * 512);
        gll16(Kg + row * 32 + ch * 8, Kb + i * 512); }
      { int row = cL >> 3, ch = (cL & 7) ^ (row & 7);
        gll16(Vg + row * 64 + ch * 8, Vb + i * 512); }
    }
    asm volatile("s_waitcnt vmcnt(0)" ::: "memory");
    __builtin_amdgcn_sched_barrier(0);

    // S = Q K^T
    s16x8 qf[4], kf[4];
#pragma unroll
    for (int mi = 0; mi < 4; ++mi) {
      int row = mi * 16 + l15;
      int ch = g ^ (row & 3);
      qf[mi] = *reinterpret_cast<const s16x8*>(&Qb[row * 32 + ch * 8]);
      kf[mi] = *reinterpret_cast<const s16x8*>(&Kb[row * 32 + ch * 8]);
    }
    f32x4 s[4][4];
#pragma unroll
    for (int mi = 0; mi < 4; ++mi)
#pragma unroll
      for (int ni = 0; ni < 4; ++ni)
        s[mi][ni] = mfma16(qf[mi], kf[ni], f32x4{0.f, 0.f, 0.f, 0.f});

    // scale + relative-position bias
#pragma unroll
    for (int mi = 0; mi < 4; ++mi)
#pragma unroll
      for (int ni = 0; ni < 4; ++ni)
#pragma unroll
        for (int r = 0; r < 4; ++r) {
          int srow = mi * 16 + g * 4 + r, tcol = ni * 16 + l15;
          int idx = ((srow >> 3) - (tcol >> 3) + 7) * 15 + ((srow & 7) - (tcol & 7) + 7);
          s[mi][ni][r] = s[mi][ni][r] * scale + btab[idx * 8 + h];
        }

    // softmax over t (cols spread across 16 lanes x 4 ni)
    float inv[4][4];
#pragma unroll
    for (int mi = 0; mi < 4; ++mi)
#pragma unroll
      for (int r = 0; r < 4; ++r) {
        float mx = fmaxf(fmaxf(s[mi][0][r], s[mi][1][r]), fmaxf(s[mi][2][r], s[mi][3][r]));
        mx = fmaxf(mx, __shfl_xor(mx, 1));
        mx = fmaxf(mx, __shfl_xor(mx, 2));
        mx = fmaxf(mx, __shfl_xor(mx, 4));
        mx = fmaxf(mx, __shfl_xor(mx, 8));
        float sum = 0.f;
#pragma unroll
        for (int ni = 0; ni < 4; ++ni) {
          float p = __expf(s[mi][ni][r] - mx);
          s[mi][ni][r] = p;
          sum += p;
        }
        sum += __shfl_xor(sum, 1);
        sum += __shfl_xor(sum, 2);
        sum += __shfl_xor(sum, 4);
        sum += __shfl_xor(sum, 8);
        inv[mi][r] = 1.0f / sum;
      }

    // P (normalized, bf16) -> LDS overlaying Q/K (register dep guarantees order)
#pragma unroll
    for (int mi = 0; mi < 4; ++mi)
#pragma unroll
      for (int ni = 0; ni < 4; ++ni)
#pragma unroll
        for (int r = 0; r < 4; ++r) {
          int row = mi * 16 + g * 4 + r, col = ni * 16 + l15;
          int byte = row * 128 + (((col >> 3) ^ (row & 7)) << 4) + (col & 7) * 2;
          *(unsigned short*)(base + byte) = f2bf(s[mi][ni][r] * inv[mi][r]);
        }
    asm volatile("s_waitcnt lgkmcnt(0)" ::: "memory");
    __builtin_amdgcn_sched_barrier(0);

    // O = P V
    f32x4 o[4][2];
#pragma unroll
    for (int mi = 0; mi < 4; ++mi)
#pragma unroll
      for (int ni = 0; ni < 2; ++ni) o[mi][ni] = f32x4{0.f, 0.f, 0.f, 0.f};
#pragma unroll
    for (int ks = 0; ks < 2; ++ks) {
      s16x8 pf[4], vf[2];
#pragma unroll
      for (int mi = 0; mi < 4; ++mi) {
        int row = mi * 16 + l15;
        int chunk = (ks * 4 + g) ^ (row & 7);
        pf[mi] = *reinterpret_cast<const s16x8*>(base + row * 128 + chunk * 16);
      }
#pragma unroll
      for (int ni = 0; ni < 2; ++ni) {
        int row = ni * 16 + l15;  // cc
        int chunk = (ks * 4 + g) ^ (row & 7);
        vf[ni] = *reinterpret_cast<const s16x8*>((unsigned char*)Vb + row * 128 + chunk * 16);
      }
#pragma unroll
      for (int mi = 0; mi < 4; ++mi)
#pragma unroll
        for (int ni = 0; ni < 2; ++ni)
          o[mi][ni] = mfma16(pf[mi], vf[ni], o[mi][ni]);
    }
#pragma unroll
    for (int mi = 0; mi < 4; ++mi)
#pragma unroll
      for (int ni = 0; ni < 2; ++ni) {
        int c = h * 32 + ni * 16 + l15;
#pragma unroll
        for (int r = 0; r < 4; ++r) {
          int m = win * 64 + mi * 16 + g * 4 + r;
          ao[(size_t)m * 256 + c] = f2bf(o[mi][ni][r]);
        }
      }
    __syncthreads();  // protect per-wave LDS reuse across head loop
  }
}

// ---------------------------------------------------------------------------
// K3: out proj GEMM + un-window/un-roll + fp32 store. M=65536, N=256, K=256.
__global__ __launch_bounds__(256) void k_oproj(const unsigned short* __restrict__ ao,
                                               const unsigned short* __restrict__ wT,
                                               const float* __restrict__ bout,
                                               float* __restrict__ out) {
  __shared__ __align__(16) unsigned short Al[128 * 64];
  __shared__ __align__(16) unsigned short Bl[128 * 64];
  int j0 = blockIdx.x * 128, m0 = blockIdx.y * 128;
  int lane = threadIdx.x & 63, w = threadIdx.x >> 6;
  int wm = w >> 1, wn = w & 1, g = lane >> 4, l15 = lane & 15;

  f32x4 acc[4][4];
#pragma unroll
  for (int i = 0; i < 4; ++i)
#pragma unroll
    for (int j = 0; j < 4; ++j) acc[i][j] = f32x4{0.f, 0.f, 0.f, 0.f};

  for (int kt = 0; kt < 4; ++kt) {
    int k0 = kt * 64;
#pragma unroll
    for (int i = 0; i < 4; ++i) {
      int r0 = (w * 4 + i) * 8;
      int row = r0 + (lane >> 3);
      int sg = (lane & 7) ^ (row & 7);
      gll16(ao + (size_t)(m0 + row) * 256 + k0 + sg * 8, &Al[r0 * 64]);
      gll16(wT + (size_t)(j0 + row) * 256 + k0 + sg * 8, &Bl[r0 * 64]);
    }
    __syncthreads();
#pragma unroll
    for (int ks = 0; ks < 2; ++ks) {
      s16x8 af[4], bf[4];
#pragma unroll
      for (int mi = 0; mi < 4; ++mi) {
        int row = wm * 64 + mi * 16 + l15;
        int chunk = (ks * 4 + g) ^ (row & 7);
        af[mi] = *reinterpret_cast<const s16x8*>(&Al[row * 64 + chunk * 8]);
      }
#pragma unroll
      for (int ni = 0; ni < 4; ++ni) {
        int row = wn * 64 + ni * 16 + l15;
        int chunk = (ks * 4 + g) ^ (row & 7);
        bf[ni] = *reinterpret_cast<const s16x8*>(&Bl[row * 64 + chunk * 8]);
      }
#pragma unroll
      for (int mi = 0; mi < 4; ++mi)
#pragma unroll
        for (int ni = 0; ni < 4; ++ni)
          acc[mi][ni] = mfma16(af[mi], bf[ni], acc[mi][ni]);
    }
    __syncthreads();
  }

#pragma unroll
  for (int ni = 0; ni < 4; ++ni) {
    int j = j0 + wn * 64 + ni * 16 + l15;
    float bj = bout[j];
#pragma unroll
    for (int mi = 0; mi < 4; ++mi) {
      int mb = m0 + wm * 64 + mi * 16 + g * 4;
      int win = mb >> 6, seq0 = mb & 63;
      int b = win >> 8, wy = (win >> 4) & 15, wx = win & 15;
      int iy = seq0 >> 3, ix0 = seq0 & 7;
      int y = (wy * 8 + iy + 4) & 127;
      int x0 = (wx * 8 + ix0 + 4) & 127;  // 4-aligned; SHIFT=4 keeps float4 contiguous
      f32x4 v = acc[mi][ni];
      v.x += bj; v.y += bj; v.z += bj; v.w += bj;
      *reinterpret_cast<f32x4*>(&out[(((size_t)b * 256 + j) << 14) + (y << 7) + x0]) = v;
    }
  }
}

// ---------------------------------------------------------------------------
extern "C" void kernel_launch(void* const* d_in, const int* in_sizes, int n_in,
                              void* d_out, int out_size, void* d_ws, size_t ws_size,
                              hipStream_t stream) {
  const float* x    = (const float*)d_in[0];
  const float* wqkv = (const float*)d_in[1];
  const float* bqkv = (const float*)d_in[2];
  const float* wout = (const float*)d_in[3];
  const float* bout = (const float*)d_in[4];
  const float* btab = (const float*)d_in[5];
  float* out = (float*)d_out;
  char* ws = (char*)d_ws;

  // workspace layout (bytes): XB/AO 33,554,432 | QKV 100,663,296 | WQ 393,216 | WO 131,072
  unsigned short* XB  = (unsigned short*)(ws);                // also reused as attention-out
  unsigned short* QKV = (unsigned short*)(ws + 33554432);
  unsigned short* WQ  = (unsigned short*)(ws + 134217728);
  unsigned short* WO  = (unsigned short*)(ws + 134610944);
  if (ws_size < 134742016ull) return;

  k_conv_x<<<1024, 256, 0, stream>>>(x, XB);
  k_conv_w<<<1024, 256, 0, stream>>>(wqkv, wout, WQ, WO);
  k_qkv<<<dim3(6, 512), 256, 0, stream>>>(XB, WQ, bqkv, QKV);
  k_attn<<<1024, 256, 0, stream>>>(QKV, btab, XB);            // XB dead -> reuse as AO
  k_oproj<<<dim3(2, 512), 256, 0, stream>>>(XB, WO, bout, out);
}

// Round 2
// 208.680 us; speedup vs baseline: 1.2857x; 1.2857x over previous
//
#include <hip/hip_runtime.h>

typedef float  f32x4  __attribute__((ext_vector_type(4)));
typedef __bf16 bf16x8 __attribute__((ext_vector_type(8)));
typedef short  s16x8  __attribute__((ext_vector_type(8)));

static __device__ __forceinline__ unsigned short f2bf(float f) {
  unsigned u = __builtin_bit_cast(unsigned, f);
  u += 0x7FFFu + ((u >> 16) & 1u);          // RNE
  return (unsigned short)(u >> 16);
}

static __device__ __forceinline__ f32x4 mfma16(s16x8 a, s16x8 b, f32x4 c) {
  return __builtin_amdgcn_mfma_f32_16x16x32_bf16(
      __builtin_bit_cast(bf16x8, a), __builtin_bit_cast(bf16x8, b), c, 0, 0, 0);
}

static __device__ __forceinline__ void gll16(const void* g, void* lds) {
  __builtin_amdgcn_global_load_lds(
      (const __attribute__((address_space(1))) unsigned int*)g,
      (__attribute__((address_space(3))) unsigned int*)lds, 16, 0, 0);
}

// ---------------------------------------------------------------------------
// K0: x[B,C,H,W] fp32 -> xb[m][c] bf16, m = window-shifted token order.
__global__ __launch_bounds__(256) void k_conv_x(const float* __restrict__ x,
                                                unsigned short* __restrict__ xb) {
  __shared__ __align__(16) unsigned short tile[64 * 264];
  int widx = blockIdx.x;
  int b = widx >> 8, wy = (widx >> 4) & 15, wx = widx & 15;
  int t = threadIdx.x;
  int tok = t & 63, cq = t >> 6;
  int iy = tok >> 3, ix = tok & 7;
  int y  = (wy * 8 + iy + 4) & 127;
  int xx = (wx * 8 + ix + 4) & 127;
  const float* px = x + ((size_t)b << 22) + (y << 7) + xx;
  for (int ci = 0; ci < 64; ++ci) {
    int c = ci * 4 + cq;
    tile[tok * 264 + c] = f2bf(px[(size_t)c << 14]);
  }
  __syncthreads();
  size_t base = (size_t)widx * 64 * 256;
  for (int it = 0; it < 8; ++it) {
    int idx = it * 256 + t;
    int tk = idx >> 5, ch = idx & 31;
    uint4 v = *reinterpret_cast<const uint4*>(&tile[tk * 264 + ch * 8]);
    *reinterpret_cast<uint4*>(&xb[base + (size_t)tk * 256 + ch * 8]) = v;
  }
}

// ---------------------------------------------------------------------------
// K0b: weight transposes -> K-minor bf16.
__global__ __launch_bounds__(256) void k_conv_w(const float* __restrict__ wqkv,
                                                const float* __restrict__ wout,
                                                unsigned short* __restrict__ wqkvT,
                                                unsigned short* __restrict__ woutT) {
  int j = blockIdx.x, c = threadIdx.x;
  if (j < 768) wqkvT[j * 256 + c] = f2bf(wqkv[c * 768 + j]);
  else { int jj = j - 768; woutT[jj * 256 + c] = f2bf(wout[c * 256 + jj]); }
}

// ---------------------------------------------------------------------------
// K1: QKV GEMM, M=65536, N=768, K=256. 128x128 tile, BK=64, 4 waves.
// Store: t<2 (Q,K): [win][t][h][seq][cc]; t==2 (V): [win][2][h][cc][seq]
__global__ __launch_bounds__(256) void k_qkv(const unsigned short* __restrict__ xb,
                                             const unsigned short* __restrict__ wT,
                                             const float* __restrict__ bqkv,
                                             unsigned short* __restrict__ qkv) {
  __shared__ __align__(16) unsigned short Al[128 * 64];
  __shared__ __align__(16) unsigned short Bl[128 * 64];
  int j0 = blockIdx.x * 128, m0 = blockIdx.y * 128;
  int lane = threadIdx.x & 63, w = threadIdx.x >> 6;
  int wm = w >> 1, wn = w & 1, g = lane >> 4, l15 = lane & 15;

  f32x4 acc[4][4];
#pragma unroll
  for (int i = 0; i < 4; ++i)
#pragma unroll
    for (int j = 0; j < 4; ++j) acc[i][j] = f32x4{0.f, 0.f, 0.f, 0.f};

  for (int kt = 0; kt < 4; ++kt) {
    int k0 = kt * 64;
#pragma unroll
    for (int i = 0; i < 4; ++i) {
      int r0 = (w * 4 + i) * 8;
      int row = r0 + (lane >> 3);
      int sg = (lane & 7) ^ (row & 7);
      gll16(xb + (size_t)(m0 + row) * 256 + k0 + sg * 8, &Al[r0 * 64]);
      gll16(wT + (size_t)(j0 + row) * 256 + k0 + sg * 8, &Bl[r0 * 64]);
    }
    __syncthreads();
#pragma unroll
    for (int ks = 0; ks < 2; ++ks) {
      s16x8 af[4], bf[4];
#pragma unroll
      for (int mi = 0; mi < 4; ++mi) {
        int row = wm * 64 + mi * 16 + l15;
        int chunk = (ks * 4 + g) ^ (row & 7);
        af[mi] = *reinterpret_cast<const s16x8*>(&Al[row * 64 + chunk * 8]);
      }
#pragma unroll
      for (int ni = 0; ni < 4; ++ni) {
        int row = wn * 64 + ni * 16 + l15;
        int chunk = (ks * 4 + g) ^ (row & 7);
        bf[ni] = *reinterpret_cast<const s16x8*>(&Bl[row * 64 + chunk * 8]);
      }
#pragma unroll
      for (int mi = 0; mi < 4; ++mi)
#pragma unroll
        for (int ni = 0; ni < 4; ++ni)
          acc[mi][ni] = mfma16(af[mi], bf[ni], acc[mi][ni]);
    }
    __syncthreads();
  }

  int t3 = j0 >> 8;
#pragma unroll
  for (int ni = 0; ni < 4; ++ni) {
    int j = j0 + wn * 64 + ni * 16 + l15;
    int h = (j >> 5) & 7, cc = j & 31;
    float bj = bqkv[j];
#pragma unroll
    for (int mi = 0; mi < 4; ++mi) {
      int mb = m0 + wm * 64 + mi * 16 + g * 4;
      int win = mb >> 6, seq0 = mb & 63;
      size_t basead = ((size_t)(win * 3 + t3) * 8 + h) * 2048;
      f32x4 v = acc[mi][ni];
      if (t3 < 2) {
#pragma unroll
        for (int r = 0; r < 4; ++r)
          qkv[basead + (size_t)(seq0 + r) * 32 + cc] = f2bf(v[r] + bj);
      } else {
        ushort4 pk;
        pk.x = f2bf(v.x + bj); pk.y = f2bf(v.y + bj);
        pk.z = f2bf(v.z + bj); pk.w = f2bf(v.w + bj);
        *reinterpret_cast<ushort4*>(&qkv[basead + (size_t)cc * 64 + seq0]) = pk;
      }
    }
  }
}

// ---------------------------------------------------------------------------
// K2 v2: one wave per (window, head). 8192 waves, no barriers.
// Swapped QK^T (S^T = K·Q^T) -> softmax mostly register-local.
// Q/K/V global->reg direct in frag layout. LDS only for P redistribution
// (8KB/wave, XOR-swizzled, write b64 / read b128, conflict-free).
__global__ __launch_bounds__(256) void k_attn(const unsigned short* __restrict__ qkv,
                                              const float* __restrict__ btab,
                                              unsigned short* __restrict__ ao) {
  __shared__ __align__(16) unsigned char sm[4 * 8192];
  int lane = threadIdx.x & 63, w = threadIdx.x >> 6;
  int task = blockIdx.x * 4 + w;
  int win = task >> 3, h = task & 7;
  unsigned char* base = sm + w * 8192;
  int g = lane >> 4, l15 = lane & 15;
  const float scale = 0.17677669529663687f;  // 1/sqrt(32)

  const unsigned short* Qg = qkv + ((size_t)(win * 3 + 0) * 8 + h) * 2048;
  const unsigned short* Kg = qkv + ((size_t)(win * 3 + 1) * 8 + h) * 2048;
  const unsigned short* Vg = qkv + ((size_t)(win * 3 + 2) * 8 + h) * 2048;

  // direct fragment loads (coalesced 16B/lane)
  s16x8 kfr[4], qfr[4], vfr[2][2];
#pragma unroll
  for (int ti = 0; ti < 4; ++ti)
    kfr[ti] = *reinterpret_cast<const s16x8*>(Kg + (ti * 16 + l15) * 32 + g * 8);
#pragma unroll
  for (int si = 0; si < 4; ++si)
    qfr[si] = *reinterpret_cast<const s16x8*>(Qg + (si * 16 + l15) * 32 + g * 8);
#pragma unroll
  for (int ni = 0; ni < 2; ++ni)
#pragma unroll
    for (int ks = 0; ks < 2; ++ks)
      vfr[ni][ks] = *reinterpret_cast<const s16x8*>(Vg + (ni * 16 + l15) * 64 + ks * 32 + g * 8);

  // S^T[t][s] = sum_c K[t][c] Q[s][c]
  f32x4 st[4][4];  // [ti][si]; value (t = ti*16+g*4+r, s = si*16+l15)
#pragma unroll
  for (int ti = 0; ti < 4; ++ti)
#pragma unroll
    for (int si = 0; si < 4; ++si)
      st[ti][si] = mfma16(kfr[ti], qfr[si], f32x4{0.f, 0.f, 0.f, 0.f});

  // scale + relative-position bias (s = query, t = key)
#pragma unroll
  for (int ti = 0; ti < 4; ++ti)
#pragma unroll
    for (int si = 0; si < 4; ++si)
#pragma unroll
      for (int r = 0; r < 4; ++r) {
        int t = ti * 16 + g * 4 + r, s = si * 16 + l15;
        int idx = ((s >> 3) - (t >> 3) + 7) * 15 + ((s & 7) - (t & 7) + 7);
        st[ti][si][r] = st[ti][si][r] * scale + btab[idx * 8 + h];
      }

  // softmax over t for each of the 4 columns s this lane owns
#pragma unroll
  for (int si = 0; si < 4; ++si) {
    float mx = st[0][si][0];
#pragma unroll
    for (int ti = 0; ti < 4; ++ti)
#pragma unroll
      for (int r = 0; r < 4; ++r) mx = fmaxf(mx, st[ti][si][r]);
    mx = fmaxf(mx, __shfl_xor(mx, 16));
    mx = fmaxf(mx, __shfl_xor(mx, 32));
    float sum = 0.f;
#pragma unroll
    for (int ti = 0; ti < 4; ++ti)
#pragma unroll
      for (int r = 0; r < 4; ++r) {
        float p = __expf(st[ti][si][r] - mx);
        st[ti][si][r] = p;
        sum += p;
      }
    sum += __shfl_xor(sum, 16);
    sum += __shfl_xor(sum, 32);
    float inv = 1.0f / sum;
    // normalized P -> LDS as [s][t], XOR-swizzled, packed b64 (4 t per write)
    int s = si * 16 + l15;
#pragma unroll
    for (int ti = 0; ti < 4; ++ti) {
      unsigned d0 = ((unsigned)f2bf(st[ti][si][1] * inv) << 16) | f2bf(st[ti][si][0] * inv);
      unsigned d1 = ((unsigned)f2bf(st[ti][si][3] * inv) << 16) | f2bf(st[ti][si][2] * inv);
      int byte = s * 128 + ((ti * 32 + g * 8) ^ ((s & 7) << 4));
      *reinterpret_cast<uint2*>(base + byte) = uint2{d0, d1};
    }
  }

  // O = P V  (pf rows s over t from LDS; vfr rows cc over t from regs)
  f32x4 o[4][2];
#pragma unroll
  for (int mi = 0; mi < 4; ++mi)
#pragma unroll
    for (int ni = 0; ni < 2; ++ni) o[mi][ni] = f32x4{0.f, 0.f, 0.f, 0.f};
#pragma unroll
  for (int ks = 0; ks < 2; ++ks) {
    s16x8 pf[4];
#pragma unroll
    for (int mi = 0; mi < 4; ++mi) {
      int s = mi * 16 + l15;
      int byte = s * 128 + ((ks * 64 + g * 16) ^ ((s & 7) << 4));
      pf[mi] = *reinterpret_cast<const s16x8*>(base + byte);
    }
#pragma unroll
    for (int mi = 0; mi < 4; ++mi)
#pragma unroll
      for (int ni = 0; ni < 2; ++ni)
        o[mi][ni] = mfma16(pf[mi], vfr[ni][ks], o[mi][ni]);
  }

#pragma unroll
  for (int mi = 0; mi < 4; ++mi)
#pragma unroll
    for (int ni = 0; ni < 2; ++ni) {
      int c = h * 32 + ni * 16 + l15;
#pragma unroll
      for (int r = 0; r < 4; ++r) {
        int m = win * 64 + mi * 16 + g * 4 + r;
        ao[(size_t)m * 256 + c] = f2bf(o[mi][ni][r]);
      }
    }
}

// ---------------------------------------------------------------------------
// K3: out proj GEMM + un-window/un-roll + fp32 store. M=65536, N=256, K=256.
__global__ __launch_bounds__(256) void k_oproj(const unsigned short* __restrict__ ao,
                                               const unsigned short* __restrict__ wT,
                                               const float* __restrict__ bout,
                                               float* __restrict__ out) {
  __shared__ __align__(16) unsigned short Al[128 * 64];
  __shared__ __align__(16) unsigned short Bl[128 * 64];
  int j0 = blockIdx.x * 128, m0 = blockIdx.y * 128;
  int lane = threadIdx.x & 63, w = threadIdx.x >> 6;
  int wm = w >> 1, wn = w & 1, g = lane >> 4, l15 = lane & 15;

  f32x4 acc[4][4];
#pragma unroll
  for (int i = 0; i < 4; ++i)
#pragma unroll
    for (int j = 0; j < 4; ++j) acc[i][j] = f32x4{0.f, 0.f, 0.f, 0.f};

  for (int kt = 0; kt < 4; ++kt) {
    int k0 = kt * 64;
#pragma unroll
    for (int i = 0; i < 4; ++i) {
      int r0 = (w * 4 + i) * 8;
      int row = r0 + (lane >> 3);
      int sg = (lane & 7) ^ (row & 7);
      gll16(ao + (size_t)(m0 + row) * 256 + k0 + sg * 8, &Al[r0 * 64]);
      gll16(wT + (size_t)(j0 + row) * 256 + k0 + sg * 8, &Bl[r0 * 64]);
    }
    __syncthreads();
#pragma unroll
    for (int ks = 0; ks < 2; ++ks) {
      s16x8 af[4], bf[4];
#pragma unroll
      for (int mi = 0; mi < 4; ++mi) {
        int row = wm * 64 + mi * 16 + l15;
        int chunk = (ks * 4 + g) ^ (row & 7);
        af[mi] = *reinterpret_cast<const s16x8*>(&Al[row * 64 + chunk * 8]);
      }
#pragma unroll
      for (int ni = 0; ni < 4; ++ni) {
        int row = wn * 64 + ni * 16 + l15;
        int chunk = (ks * 4 + g) ^ (row & 7);
        bf[ni] = *reinterpret_cast<const s16x8*>(&Bl[row * 64 + chunk * 8]);
      }
#pragma unroll
      for (int mi = 0; mi < 4; ++mi)
#pragma unroll
        for (int ni = 0; ni < 4; ++ni)
          acc[mi][ni] = mfma16(af[mi], bf[ni], acc[mi][ni]);
    }
    __syncthreads();
  }

#pragma unroll
  for (int ni = 0; ni < 4; ++ni) {
    int j = j0 + wn * 64 + ni * 16 + l15;
    float bj = bout[j];
#pragma unroll
    for (int mi = 0; mi < 4; ++mi) {
      int mb = m0 + wm * 64 + mi * 16 + g * 4;
      int win = mb >> 6, seq0 = mb & 63;
      int b = win >> 8, wy = (win >> 4) & 15, wx = win & 15;
      int iy = seq0 >> 3, ix0 = seq0 & 7;
      int y = (wy * 8 + iy + 4) & 127;
      int x0 = (wx * 8 + ix0 + 4) & 127;
      f32x4 v = acc[mi][ni];
      v.x += bj; v.y += bj; v.z += bj; v.w += bj;
      *reinterpret_cast<f32x4*>(&out[(((size_t)b * 256 + j) << 14) + (y << 7) + x0]) = v;
    }
  }
}

// ---------------------------------------------------------------------------
extern "C" void kernel_launch(void* const* d_in, const int* in_sizes, int n_in,
                              void* d_out, int out_size, void* d_ws, size_t ws_size,
                              hipStream_t stream) {
  const float* x    = (const float*)d_in[0];
  const float* wqkv = (const float*)d_in[1];
  const float* bqkv = (const float*)d_in[2];
  const float* wout = (const float*)d_in[3];
  const float* bout = (const float*)d_in[4];
  const float* btab = (const float*)d_in[5];
  float* out = (float*)d_out;
  char* ws = (char*)d_ws;

  unsigned short* XB  = (unsigned short*)(ws);                // reused as attention-out
  unsigned short* QKV = (unsigned short*)(ws + 33554432);
  unsigned short* WQ  = (unsigned short*)(ws + 134217728);
  unsigned short* WO  = (unsigned short*)(ws + 134610944);
  if (ws_size < 134742016ull) return;

  k_conv_x<<<1024, 256, 0, stream>>>(x, XB);
  k_conv_w<<<1024, 256, 0, stream>>>(wqkv, wout, WQ, WO);
  k_qkv<<<dim3(6, 512), 256, 0, stream>>>(XB, WQ, bqkv, QKV);
  k_attn<<<2048, 256, 0, stream>>>(QKV, btab, XB);
  k_oproj<<<dim3(2, 512), 256, 0, stream>>>(XB, WO, bout, out);
}

// Round 3
// 160.903 us; speedup vs baseline: 1.6675x; 1.2969x over previous
//
#include <hip/hip_runtime.h>

typedef float  f32x4  __attribute__((ext_vector_type(4)));
typedef __bf16 bf16x8 __attribute__((ext_vector_type(8)));
typedef short  s16x8  __attribute__((ext_vector_type(8)));

static __device__ __forceinline__ unsigned short f2bf(float f) {
  unsigned u = __builtin_bit_cast(unsigned, f);
  u += 0x7FFFu + ((u >> 16) & 1u);          // RNE
  return (unsigned short)(u >> 16);
}

static __device__ __forceinline__ f32x4 mfma16(s16x8 a, s16x8 b, f32x4 c) {
  return __builtin_amdgcn_mfma_f32_16x16x32_bf16(
      __builtin_bit_cast(bf16x8, a), __builtin_bit_cast(bf16x8, b), c, 0, 0, 0);
}

static __device__ __forceinline__ void gll16(const void* g, void* lds) {
  __builtin_amdgcn_global_load_lds(
      (const __attribute__((address_space(1))) unsigned int*)g,
      (__attribute__((address_space(3))) unsigned int*)lds, 16, 0, 0);
}

// ---------------------------------------------------------------------------
// K0 v2: x[B,C,H,W] fp32 -> xb[m][c] bf16 (window-shifted token order) with
// coalesced row reads + LDS transpose.
// Block = (b, wy, h2 half-band, 32-ch chunk): 1024 blocks.
// LDS rows indexed sigma = lr*128 + ix*16 + wx (stride 40 ushorts) so the
// scattered transpose writes hit ~contiguous rows and reads stay b128-aligned.
__global__ __launch_bounds__(256) void k_conv_x(const float* __restrict__ x,
                                                unsigned short* __restrict__ xb) {
  __shared__ __align__(16) unsigned short L[512 * 40];
  int bid = blockIdx.x;
  int cchunk = bid & 7, h2 = (bid >> 3) & 1, wy = (bid >> 4) & 15, b = bid >> 8;
  int t = threadIdx.x;
  int cpair = t >> 7, slot = t & 127, lr = slot >> 5, lp = slot & 31;
  int y = (wy * 8 + h2 * 4 + lr + 4) & 127;
  const float* row0 = x + ((size_t)b << 22) + (y << 7);
  int cbase = cchunk * 32;

  for (int it = 0; it < 8; ++it) {
    int cL0 = it * 4 + cpair * 2;
    const float* pa = row0 + ((size_t)(cbase + cL0) << 14) + lp * 4;
    f32x4 a  = *reinterpret_cast<const f32x4*>(pa);
    f32x4 c4 = *reinterpret_cast<const f32x4*>(pa + 16384);
#pragma unroll
    for (int i = 0; i < 4; ++i) {
      int xc = lp * 4 + i;
      int xp = (xc - 4) & 127;                  // un-rolled x'
      int wx = xp >> 3, ix = xp & 7;
      int sg = lr * 128 + ix * 16 + wx;
      unsigned pk = (unsigned)f2bf(a[i]) | ((unsigned)f2bf(c4[i]) << 16);
      *reinterpret_cast<unsigned*>(&L[sg * 40 + cL0]) = pk;
    }
  }
  __syncthreads();

  size_t M0 = ((size_t)((b * 16 + wy) * 16)) * 64 + h2 * 32;
  for (int pass = 0; pass < 8; ++pass) {
    int tk = pass * 64 + (t >> 2), p = t & 3;
    int wx = tk >> 5, lr2 = (tk >> 3) & 3, ix = tk & 7;
    int sg = lr2 * 128 + ix * 16 + wx;
    uint4 v = *reinterpret_cast<const uint4*>(&L[sg * 40 + p * 8]);
    size_t m = M0 + (size_t)wx * 64 + lr2 * 8 + ix;
    *reinterpret_cast<uint4*>(&xb[m * 256 + cbase + p * 8]) = v;
  }
}

// ---------------------------------------------------------------------------
// K0b: weight transposes -> K-minor bf16.
__global__ __launch_bounds__(256) void k_conv_w(const float* __restrict__ wqkv,
                                                const float* __restrict__ wout,
                                                unsigned short* __restrict__ wqkvT,
                                                unsigned short* __restrict__ woutT) {
  int j = blockIdx.x, c = threadIdx.x;
  if (j < 768) wqkvT[j * 256 + c] = f2bf(wqkv[c * 768 + j]);
  else { int jj = j - 768; woutT[jj * 256 + c] = f2bf(wout[c * 256 + jj]); }
}

// ---------------------------------------------------------------------------
// K1: QKV GEMM, M=65536, N=768, K=256. 128x128 tile, BK=64, 4 waves.
// Store: t<2 (Q,K): [win][t][h][seq][cc]; t==2 (V): [win][2][h][cc][seq]
__global__ __launch_bounds__(256) void k_qkv(const unsigned short* __restrict__ xb,
                                             const unsigned short* __restrict__ wT,
                                             const float* __restrict__ bqkv,
                                             unsigned short* __restrict__ qkv) {
  __shared__ __align__(16) unsigned short Al[128 * 64];
  __shared__ __align__(16) unsigned short Bl[128 * 64];
  int j0 = blockIdx.x * 128, m0 = blockIdx.y * 128;
  int lane = threadIdx.x & 63, w = threadIdx.x >> 6;
  int wm = w >> 1, wn = w & 1, g = lane >> 4, l15 = lane & 15;

  f32x4 acc[4][4];
#pragma unroll
  for (int i = 0; i < 4; ++i)
#pragma unroll
    for (int j = 0; j < 4; ++j) acc[i][j] = f32x4{0.f, 0.f, 0.f, 0.f};

  for (int kt = 0; kt < 4; ++kt) {
    int k0 = kt * 64;
#pragma unroll
    for (int i = 0; i < 4; ++i) {
      int r0 = (w * 4 + i) * 8;
      int row = r0 + (lane >> 3);
      int sg = (lane & 7) ^ (row & 7);
      gll16(xb + (size_t)(m0 + row) * 256 + k0 + sg * 8, &Al[r0 * 64]);
      gll16(wT + (size_t)(j0 + row) * 256 + k0 + sg * 8, &Bl[r0 * 64]);
    }
    __syncthreads();
#pragma unroll
    for (int ks = 0; ks < 2; ++ks) {
      s16x8 af[4], bf[4];
#pragma unroll
      for (int mi = 0; mi < 4; ++mi) {
        int row = wm * 64 + mi * 16 + l15;
        int chunk = (ks * 4 + g) ^ (row & 7);
        af[mi] = *reinterpret_cast<const s16x8*>(&Al[row * 64 + chunk * 8]);
      }
#pragma unroll
      for (int ni = 0; ni < 4; ++ni) {
        int row = wn * 64 + ni * 16 + l15;
        int chunk = (ks * 4 + g) ^ (row & 7);
        bf[ni] = *reinterpret_cast<const s16x8*>(&Bl[row * 64 + chunk * 8]);
      }
#pragma unroll
      for (int mi = 0; mi < 4; ++mi)
#pragma unroll
        for (int ni = 0; ni < 4; ++ni)
          acc[mi][ni] = mfma16(af[mi], bf[ni], acc[mi][ni]);
    }
    __syncthreads();
  }

  int t3 = j0 >> 8;
#pragma unroll
  for (int ni = 0; ni < 4; ++ni) {
    int j = j0 + wn * 64 + ni * 16 + l15;
    int h = (j >> 5) & 7, cc = j & 31;
    float bj = bqkv[j];
#pragma unroll
    for (int mi = 0; mi < 4; ++mi) {
      int mb = m0 + wm * 64 + mi * 16 + g * 4;
      int win = mb >> 6, seq0 = mb & 63;
      size_t basead = ((size_t)(win * 3 + t3) * 8 + h) * 2048;
      f32x4 v = acc[mi][ni];
      if (t3 < 2) {
#pragma unroll
        for (int r = 0; r < 4; ++r)
          qkv[basead + (size_t)(seq0 + r) * 32 + cc] = f2bf(v[r] + bj);
      } else {
        ushort4 pk;
        pk.x = f2bf(v.x + bj); pk.y = f2bf(v.y + bj);
        pk.z = f2bf(v.z + bj); pk.w = f2bf(v.w + bj);
        *reinterpret_cast<ushort4*>(&qkv[basead + (size_t)cc * 64 + seq0]) = pk;
      }
    }
  }
}

// ---------------------------------------------------------------------------
// K2: one wave per (window, head). 8192 waves, no barriers.
__global__ __launch_bounds__(256) void k_attn(const unsigned short* __restrict__ qkv,
                                              const float* __restrict__ btab,
                                              unsigned short* __restrict__ ao) {
  __shared__ __align__(16) unsigned char sm[4 * 8192];
  int lane = threadIdx.x & 63, w = threadIdx.x >> 6;
  int task = blockIdx.x * 4 + w;
  int win = task >> 3, h = task & 7;
  unsigned char* base = sm + w * 8192;
  int g = lane >> 4, l15 = lane & 15;
  const float scale = 0.17677669529663687f;  // 1/sqrt(32)

  const unsigned short* Qg = qkv + ((size_t)(win * 3 + 0) * 8 + h) * 2048;
  const unsigned short* Kg = qkv + ((size_t)(win * 3 + 1) * 8 + h) * 2048;
  const unsigned short* Vg = qkv + ((size_t)(win * 3 + 2) * 8 + h) * 2048;

  s16x8 kfr[4], qfr[4], vfr[2][2];
#pragma unroll
  for (int ti = 0; ti < 4; ++ti)
    kfr[ti] = *reinterpret_cast<const s16x8*>(Kg + (ti * 16 + l15) * 32 + g * 8);
#pragma unroll
  for (int si = 0; si < 4; ++si)
    qfr[si] = *reinterpret_cast<const s16x8*>(Qg + (si * 16 + l15) * 32 + g * 8);
#pragma unroll
  for (int ni = 0; ni < 2; ++ni)
#pragma unroll
    for (int ks = 0; ks < 2; ++ks)
      vfr[ni][ks] = *reinterpret_cast<const s16x8*>(Vg + (ni * 16 + l15) * 64 + ks * 32 + g * 8);

  f32x4 st[4][4];
#pragma unroll
  for (int ti = 0; ti < 4; ++ti)
#pragma unroll
    for (int si = 0; si < 4; ++si)
      st[ti][si] = mfma16(kfr[ti], qfr[si], f32x4{0.f, 0.f, 0.f, 0.f});

#pragma unroll
  for (int ti = 0; ti < 4; ++ti)
#pragma unroll
    for (int si = 0; si < 4; ++si)
#pragma unroll
      for (int r = 0; r < 4; ++r) {
        int tt = ti * 16 + g * 4 + r, s = si * 16 + l15;
        int idx = ((s >> 3) - (tt >> 3) + 7) * 15 + ((s & 7) - (tt & 7) + 7);
        st[ti][si][r] = st[ti][si][r] * scale + btab[idx * 8 + h];
      }

#pragma unroll
  for (int si = 0; si < 4; ++si) {
    float mx = st[0][si][0];
#pragma unroll
    for (int ti = 0; ti < 4; ++ti)
#pragma unroll
      for (int r = 0; r < 4; ++r) mx = fmaxf(mx, st[ti][si][r]);
    mx = fmaxf(mx, __shfl_xor(mx, 16));
    mx = fmaxf(mx, __shfl_xor(mx, 32));
    float sum = 0.f;
#pragma unroll
    for (int ti = 0; ti < 4; ++ti)
#pragma unroll
      for (int r = 0; r < 4; ++r) {
        float p = __expf(st[ti][si][r] - mx);
        st[ti][si][r] = p;
        sum += p;
      }
    sum += __shfl_xor(sum, 16);
    sum += __shfl_xor(sum, 32);
    float inv = 1.0f / sum;
    int s = si * 16 + l15;
#pragma unroll
    for (int ti = 0; ti < 4; ++ti) {
      unsigned d0 = ((unsigned)f2bf(st[ti][si][1] * inv) << 16) | f2bf(st[ti][si][0] * inv);
      unsigned d1 = ((unsigned)f2bf(st[ti][si][3] * inv) << 16) | f2bf(st[ti][si][2] * inv);
      int byte = s * 128 + ((ti * 32 + g * 8) ^ ((s & 7) << 4));
      *reinterpret_cast<uint2*>(base + byte) = uint2{d0, d1};
    }
  }

  f32x4 o[4][2];
#pragma unroll
  for (int mi = 0; mi < 4; ++mi)
#pragma unroll
    for (int ni = 0; ni < 2; ++ni) o[mi][ni] = f32x4{0.f, 0.f, 0.f, 0.f};
#pragma unroll
  for (int ks = 0; ks < 2; ++ks) {
    s16x8 pf[4];
#pragma unroll
    for (int mi = 0; mi < 4; ++mi) {
      int s = mi * 16 + l15;
      int byte = s * 128 + ((ks * 64 + g * 16) ^ ((s & 7) << 4));
      pf[mi] = *reinterpret_cast<const s16x8*>(base + byte);
    }
#pragma unroll
    for (int mi = 0; mi < 4; ++mi)
#pragma unroll
      for (int ni = 0; ni < 2; ++ni)
        o[mi][ni] = mfma16(pf[mi], vfr[ni][ks], o[mi][ni]);
  }

#pragma unroll
  for (int mi = 0; mi < 4; ++mi)
#pragma unroll
    for (int ni = 0; ni < 2; ++ni) {
      int c = h * 32 + ni * 16 + l15;
#pragma unroll
      for (int r = 0; r < 4; ++r) {
        int m = win * 64 + mi * 16 + g * 4 + r;
        ao[(size_t)m * 256 + c] = f2bf(o[mi][ni][r]);
      }
    }
}

// ---------------------------------------------------------------------------
// K3: out proj GEMM + un-window/un-roll + fp32 store. M=65536, N=256, K=256.
__global__ __launch_bounds__(256) void k_oproj(const unsigned short* __restrict__ ao,
                                               const unsigned short* __restrict__ wT,
                                               const float* __restrict__ bout,
                                               float* __restrict__ out) {
  __shared__ __align__(16) unsigned short Al[128 * 64];
  __shared__ __align__(16) unsigned short Bl[128 * 64];
  int j0 = blockIdx.x * 128, m0 = blockIdx.y * 128;
  int lane = threadIdx.x & 63, w = threadIdx.x >> 6;
  int wm = w >> 1, wn = w & 1, g = lane >> 4, l15 = lane & 15;

  f32x4 acc[4][4];
#pragma unroll
  for (int i = 0; i < 4; ++i)
#pragma unroll
    for (int j = 0; j < 4; ++j) acc[i][j] = f32x4{0.f, 0.f, 0.f, 0.f};

  for (int kt = 0; kt < 4; ++kt) {
    int k0 = kt * 64;
#pragma unroll
    for (int i = 0; i < 4; ++i) {
      int r0 = (w * 4 + i) * 8;
      int row = r0 + (lane >> 3);
      int sg = (lane & 7) ^ (row & 7);
      gll16(ao + (size_t)(m0 + row) * 256 + k0 + sg * 8, &Al[r0 * 64]);
      gll16(wT + (size_t)(j0 + row) * 256 + k0 + sg * 8, &Bl[r0 * 64]);
    }
    __syncthreads();
#pragma unroll
    for (int ks = 0; ks < 2; ++ks) {
      s16x8 af[4], bf[4];
#pragma unroll
      for (int mi = 0; mi < 4; ++mi) {
        int row = wm * 64 + mi * 16 + l15;
        int chunk = (ks * 4 + g) ^ (row & 7);
        af[mi] = *reinterpret_cast<const s16x8*>(&Al[row * 64 + chunk * 8]);
      }
#pragma unroll
      for (int ni = 0; ni < 4; ++ni) {
        int row = wn * 64 + ni * 16 + l15;
        int chunk = (ks * 4 + g) ^ (row & 7);
        bf[ni] = *reinterpret_cast<const s16x8*>(&Bl[row * 64 + chunk * 8]);
      }
#pragma unroll
      for (int mi = 0; mi < 4; ++mi)
#pragma unroll
        for (int ni = 0; ni < 4; ++ni)
          acc[mi][ni] = mfma16(af[mi], bf[ni], acc[mi][ni]);
    }
    __syncthreads();
  }

#pragma unroll
  for (int ni = 0; ni < 4; ++ni) {
    int j = j0 + wn * 64 + ni * 16 + l15;
    float bj = bout[j];
#pragma unroll
    for (int mi = 0; mi < 4; ++mi) {
      int mb = m0 + wm * 64 + mi * 16 + g * 4;
      int win = mb >> 6, seq0 = mb & 63;
      int b = win >> 8, wy = (win >> 4) & 15, wx = win & 15;
      int iy = seq0 >> 3, ix0 = seq0 & 7;
      int y = (wy * 8 + iy + 4) & 127;
      int x0 = (wx * 8 + ix0 + 4) & 127;
      f32x4 v = acc[mi][ni];
      v.x += bj; v.y += bj; v.z += bj; v.w += bj;
      *reinterpret_cast<f32x4*>(&out[(((size_t)b * 256 + j) << 14) + (y << 7) + x0]) = v;
    }
  }
}

// ---------------------------------------------------------------------------
extern "C" void kernel_launch(void* const* d_in, const int* in_sizes, int n_in,
                              void* d_out, int out_size, void* d_ws, size_t ws_size,
                              hipStream_t stream) {
  const float* x    = (const float*)d_in[0];
  const float* wqkv = (const float*)d_in[1];
  const float* bqkv = (const float*)d_in[2];
  const float* wout = (const float*)d_in[3];
  const float* bout = (const float*)d_in[4];
  const float* btab = (const float*)d_in[5];
  float* out = (float*)d_out;
  char* ws = (char*)d_ws;

  unsigned short* XB  = (unsigned short*)(ws);                // reused as attention-out
  unsigned short* QKV = (unsigned short*)(ws + 33554432);
  unsigned short* WQ  = (unsigned short*)(ws + 134217728);
  unsigned short* WO  = (unsigned short*)(ws + 134610944);
  if (ws_size < 134742016ull) return;

  k_conv_x<<<1024, 256, 0, stream>>>(x, XB);
  k_conv_w<<<1024, 256, 0, stream>>>(wqkv, wout, WQ, WO);
  k_qkv<<<dim3(6, 512), 256, 0, stream>>>(XB, WQ, bqkv, QKV);
  k_attn<<<2048, 256, 0, stream>>>(QKV, btab, XB);
  k_oproj<<<dim3(2, 512), 256, 0, stream>>>(XB, WO, bout, out);
}